// Round 6
// baseline (123.449 us; speedup 1.0000x reference)
//
#include <hip/hip_runtime.h>
#include <math.h>

#pragma clang fp contract(off)

#define N_ROIS     1500
#define NUM_CLS    81
#define FG         80
#define MAXC       1536      // per-class candidate capacity (worst case N_ROIS)
#define NMS_T      0.5f
#define SCORE_T    0.05f
#define MAX_DET    100
#define TOTAL      (FG * N_ROIS)
#define TPB        256

// float <-> order-preserving uint
__device__ __forceinline__ unsigned f2s(float f) {
    unsigned u = __float_as_uint(f);
    return (u & 0x80000000u) ? ~u : (u | 0x80000000u);
}
__device__ __forceinline__ float s2f(unsigned u) {
    return __uint_as_float((u & 0x80000000u) ? (u & 0x7FFFFFFFu) : ~u);
}

// One block (256 threads) per foreground class, fully fused:
//  compact valid (s > 0.05) via wave-ballot -> rank-by-counting sort (keys
//  unique: score desc, idx asc => exact stable order) -> decode valid boxes
//  -> bitmask NMS (MxM suppression bit-matrix via __ballot, register-only
//  serial scan on wave 0; iterative fallback if matrix exceeds LDS) ->
//  push kept entries to a global compact list. The LAST block to finish
//  (device-scope done-counter) then runs the exact radix-256 top-100 select
//  and scatters kept rows into out.
// Exactness of compaction: all valid scores strictly exceed all invalid
// ones, so valid-only stable rank == full stable rank; non-kept rows emit
// zeros so only valid rows ever need boxes/scores.
__global__ __launch_bounds__(TPB) void nms_fused(
    const float* __restrict__ rois,    // (N,5)
    const float* __restrict__ deltas,  // (N, 4*81)
    const float* __restrict__ prob,    // (N, 81)
    const float* __restrict__ iminfo,  // (1,3)
    float4* __restrict__ keptBox,
    int*    __restrict__ keptRow,
    float*  __restrict__ keptScore,
    int*    __restrict__ ctrs,         // [0]=kept count, [1]=done count
    float*  __restrict__ out)
{
    __shared__ unsigned long long key[MAXC];   // keys; then mask matrix; then topk stage
    __shared__ unsigned long long skey[MAXC];  // rank-sorted keys
    __shared__ float4 box4[MAXC];
    __shared__ float  areaA[MAXC];
    __shared__ unsigned char keepf[MAXC], supp[MAXC];
    __shared__ int hist[256];
    __shared__ int gsum[64];
    __shared__ unsigned s_pref;
    __shared__ int s_kk;
    __shared__ int mcnt, s_arr;                // total ~59.8 KB

    const int tid  = threadIdx.x;
    const int lane = tid & 63;
    const int c = blockIdx.x + 1;   // class 1..80
    const int cbase = blockIdx.x * N_ROIS;

    if (tid == 0) mcnt = 0;
    __syncthreads();

    // --- wave-aggregated compaction (24 LDS atomics instead of ~1500) ---
    for (int i0 = 0; i0 < N_ROIS; i0 += TPB) {
        int i = i0 + tid;
        float s = 0.0f;
        bool val = false;
        if (i < N_ROIS) { s = prob[i * NUM_CLS + c]; val = (s > SCORE_T); }
        unsigned long long m = __ballot(val);
        int base = 0;
        if (lane == 0 && m) base = atomicAdd(&mcnt, __popcll(m));
        base = __shfl(base, 0, 64);
        if (val) {
            int pos = base + __popcll(m & ((1ull << lane) - 1ull));
            key[pos] = ((unsigned long long)(~f2s(s)) << 32) | (unsigned)i;
        }
    }

    // --- zero-fill this class's output region (float4; all 16B-aligned) ---
    {
        const float4 z4 = make_float4(0.f, 0.f, 0.f, 0.f);
        float4* dets4 = (float4*)(out + (size_t)cbase * 6);         // 2250
        for (int i = tid; i < N_ROIS * 6 / 4; i += TPB) dets4[i] = z4;
        const float fc = (float)c;
        const float4 c4 = make_float4(fc, fc, fc, fc);
        float4* cls4  = (float4*)(out + (size_t)TOTAL * 6 + cbase); // 375
        float4* keep4 = (float4*)(out + (size_t)TOTAL * 7 + cbase);
        for (int i = tid; i < N_ROIS / 4; i += TPB) { cls4[i] = c4; keep4[i] = z4; }
    }
    __syncthreads();
    const int M = mcnt;

    if (M > 0) {
        // --- rank-by-counting sort: keys unique -> ranks are a permutation ---
        for (int i = tid; i < M; i += TPB) {
            unsigned long long kk = key[i];
            int cnt = 0;
            #pragma unroll 4
            for (int j = 0; j < M; ++j) cnt += (int)(key[j] < kk);
            skey[cnt] = kk;
        }
        __syncthreads();

        // --- decode boxes at sorted positions (match numpy op-for-op) ---
        const float Hm1 = iminfo[0] - 1.0f;
        const float Wm1 = iminfo[1] - 1.0f;
        for (int k = tid; k < M; k += TPB) {
            unsigned long long kk = skey[k];
            int i = (int)(kk & 0xFFFFFFFFu);
            const float* rp = rois + i * 5;
            float x1 = rp[1], y1 = rp[2], x2 = rp[3], y2 = rp[4];
            float w  = x2 - x1 + 1.0f;
            float h  = y2 - y1 + 1.0f;
            float cx = x1 + 0.5f * w;
            float cy = y1 + 0.5f * h;
            const float* dp = deltas + i * (4 * NUM_CLS) + c * 4;
            float dx = dp[0] / 10.0f, dy = dp[1] / 10.0f;
            float dw = dp[2] / 5.0f,  dh = dp[3] / 5.0f;
            float pcx = cx + w * dx;
            float pcy = cy + h * dy;
            float pw  = w * expf(dw);
            float ph  = h * expf(dh);
            float a1 = pcx - 0.5f * pw;
            float a2 = pcy - 0.5f * ph;
            float a3 = pcx + 0.5f * pw - 1.0f;
            float a4 = pcy + 0.5f * ph - 1.0f;
            a1 = fminf(fmaxf(a1, 0.0f), Wm1);
            a2 = fminf(fmaxf(a2, 0.0f), Hm1);
            a3 = fminf(fmaxf(a3, 0.0f), Wm1);
            a4 = fminf(fmaxf(a4, 0.0f), Hm1);
            box4[k]  = make_float4(a1, a2, a3, a4);
            areaA[k] = (a3 - a1 + 1.0f) * (a4 - a2 + 1.0f);
            keepf[k] = 0; supp[k] = 0;
        }
        __syncthreads();

        const int MW = (M + 63) >> 6;          // 64-bit words per mask row
        const bool fast = (M * MW <= MAXC);    // mask matrix fits in key[]

        if (fast) {
            // --- suppression bit-matrix: row r, bit j iff j>r && iou>0.5 ---
            const int wv = tid >> 6;
            for (int r = wv; r < M; r += TPB / 64) {
                float4 br = box4[r];
                float  ar = areaA[r];
                for (int w = 0; w < MW; ++w) {
                    int col = (w << 6) | lane;
                    bool inb = (col < M);
                    int j = inb ? col : 0;
                    float4 bj = box4[j];
                    float  aj = areaA[j];
                    float iw = fminf(br.z, bj.z) - fmaxf(br.x, bj.x) + 1.0f;
                    float ih = fminf(br.w, bj.w) - fmaxf(br.y, bj.y) + 1.0f;
                    iw = fmaxf(iw, 0.0f);
                    ih = fmaxf(ih, 0.0f);
                    float inter = iw * ih;
                    float iou = inter / ((ar + aj) - inter);
                    bool pred = inb && (col > r) && (iou > NMS_T);
                    unsigned long long mk = __ballot(pred);
                    if (lane == 0) key[r * MW + w] = mk;
                }
            }
            __syncthreads();

            // --- serial scan, wave 0, register-only chain ---
            if (tid < 64) {
                const int lw = (tid < MW) ? tid : 0;
                unsigned long long acc = 0;   // suppressed bits, word `tid`
                for (int k = 0; k < M; ++k) {
                    unsigned long long m = key[k * MW + lw];
                    int bit = (int)((acc >> (k & 63)) & 1ull);
                    int sup = __shfl(bit, k >> 6, 64);
                    if (!sup) {                // wave-uniform branch
                        acc |= m;
                        if (tid == 0) keepf[k] = 1;
                    }
                }
            }
            __syncthreads();
        } else {
            // --- fallback: iterative greedy NMS (correct for any M) ---
            for (int k = 0; k < M; ++k) {
                if (!supp[k]) {
                    if (tid == 0) keepf[k] = 1;
                    float4 bk = box4[k];
                    float  ak = areaA[k];
                    for (int j = k + 1 + tid; j < M; j += TPB) {
                        float4 bj = box4[j];
                        float  aj = areaA[j];
                        float iw = fminf(bk.z, bj.z) - fmaxf(bk.x, bj.x) + 1.0f;
                        float ih = fminf(bk.w, bj.w) - fmaxf(bk.y, bj.y) + 1.0f;
                        iw = fmaxf(iw, 0.0f);
                        ih = fmaxf(ih, 0.0f);
                        float inter = iw * ih;
                        float iou = inter / ((ak + aj) - inter);
                        if (iou > NMS_T) supp[j] = 1;
                    }
                }
                __syncthreads();
            }
        }

        // --- push kept entries to global compact list ---
        for (int k = tid; k < M; k += TPB) {
            if (keepf[k]) {
                int p = atomicAdd(&ctrs[0], 1);
                keptRow[p]   = cbase + k;
                keptBox[p]   = box4[k];
                keptScore[p] = s2f(~(unsigned)(skey[k] >> 32));
            }
        }
    }

    // --- last-block-done: the final arriving block runs topk + scatter ---
    __threadfence();                           // release our pushes device-wide
    if (tid == 0) s_arr = atomicAdd(&ctrs[1], 1);
    __syncthreads();
    if (s_arr != FG - 1) return;
    __threadfence();                           // acquire all blocks' pushes

    const int n = ctrs[0];
    const bool filt = (n > MAX_DET);
    float kth = -INFINITY;

    if (filt) {
        // exact 100th-largest via MSB-first radix-256 select (tie-exact)
        unsigned* sbits = (unsigned*)key;      // reuse: 3072-uint capacity
        const bool useLds = (n <= 2 * MAXC);
        if (useLds)
            for (int i = tid; i < n; i += TPB) sbits[i] = f2s(keptScore[i]);
        if (tid == 0) { s_pref = 0u; s_kk = MAX_DET; }
        __syncthreads();
        for (int d = 0; d < 4; ++d) {
            const int shift = 24 - 8 * d;
            if (tid < 256) hist[tid] = 0;
            __syncthreads();
            const unsigned pref = s_pref;
            for (int i = tid; i < n; i += TPB) {
                unsigned u = useLds ? sbits[i] : f2s(keptScore[i]);
                if (d == 0 || (u >> (shift + 8)) == pref)
                    atomicAdd(&hist[(u >> shift) & 255u], 1);
            }
            __syncthreads();
            if (tid < 64) {
                int g = tid;
                gsum[g] = hist[4*g] + hist[4*g+1] + hist[4*g+2] + hist[4*g+3];
            }
            if (tid == 0) {
                int kk = s_kk;
                int acc = 0;
                int g = 63;
                for (; g > 0; --g) {
                    int gs = gsum[g];
                    if (acc + gs >= kk) break;
                    acc += gs;
                }
                int v = 4 * g + 3;
                for (; v > 4 * g; --v) {
                    int h = hist[v];
                    if (acc + h >= kk) break;
                    acc += h;
                }
                s_pref = (pref << 8) | (unsigned)v;
                s_kk = kk - acc;
            }
            __syncthreads();
        }
        kth = s2f(s_pref);
    }

    for (int i = tid; i < n; i += TPB) {
        float s = keptScore[i];
        if (!filt || s >= kth) {
            int r = keptRow[i];
            float4 b4 = keptBox[i];
            float* dst = out + (size_t)r * 6;
            dst[1] = b4.x; dst[2] = b4.y; dst[3] = b4.z; dst[4] = b4.w; dst[5] = s;
            out[(size_t)TOTAL * 7 + r] = 1.0f;
        }
    }
}

extern "C" void kernel_launch(void* const* d_in, const int* in_sizes, int n_in,
                              void* d_out, int out_size, void* d_ws, size_t ws_size,
                              hipStream_t stream) {
    const float* rois   = (const float*)d_in[0];  // (1500,5)
    const float* deltas = (const float*)d_in[1];  // (1500,324)
    const float* prob   = (const float*)d_in[2];  // (1500,81)
    const float* iminfo = (const float*)d_in[3];  // (1,3)
    float* out = (float*)d_out;

    // workspace: float4 first for 16B alignment
    float4* keptBox   = (float4*)d_ws;                 // TOTAL entries
    int*    keptRow   = (int*)(keptBox + TOTAL);       // TOTAL
    float*  keptScore = (float*)(keptRow + TOTAL);     // TOTAL
    int*    ctrs      = (int*)(keptScore + TOTAL);     // [kept, done]

    hipMemsetAsync(ctrs, 0, 2 * sizeof(int), stream);
    nms_fused<<<FG, TPB, 0, stream>>>(rois, deltas, prob, iminfo,
                                      keptBox, keptRow, keptScore, ctrs, out);
}

// Round 7
// 117.798 us; speedup vs baseline: 1.0480x; 1.0480x over previous
//
#include <hip/hip_runtime.h>
#include <math.h>

#pragma clang fp contract(off)

#define N_ROIS     1500
#define NUM_CLS    81
#define FG         80
#define MAXC       1536      // per-class candidate capacity (worst case N_ROIS)
#define NMS_T      0.5f
#define SCORE_T    0.05f
#define MAX_DET    100
#define TOTAL      (FG * N_ROIS)
#define TPB        256
#define NCHUNK     ((N_ROIS + TPB - 1) / TPB)   // 6

// float <-> order-preserving uint
__device__ __forceinline__ unsigned f2s(float f) {
    unsigned u = __float_as_uint(f);
    return (u & 0x80000000u) ? ~u : (u | 0x80000000u);
}
__device__ __forceinline__ float s2f(unsigned u) {
    return __uint_as_float((u & 0x80000000u) ? (u & 0x7FFFFFFFu) : ~u);
}

// One block (256 threads) per foreground class, fully fused:
//  wave-ballot compaction of valid (s > 0.05) -> rank-by-counting sort
//  (keys unique: score desc, idx asc => exact stable order) -> decode valid
//  boxes -> bitmask NMS (MxM suppression bit-matrix via __ballot, prefetched
//  register-only serial scan on wave 0; iterative fallback if the matrix
//  exceeds LDS) -> push kept entries to a global compact list. The LAST
//  block (device-scope done-counter) runs the exact radix-256 top-100
//  select (parallel suffix-scan digit selection) and scatters kept rows.
// Exactness of compaction: all valid scores strictly exceed all invalid
// ones, so valid-only stable rank == full stable rank; non-kept rows emit
// zeros so only valid rows ever need boxes/scores.
__global__ __launch_bounds__(TPB) void nms_fused(
    const float* __restrict__ rois,    // (N,5)
    const float* __restrict__ deltas,  // (N, 4*81)
    const float* __restrict__ prob,    // (N, 81)
    const float* __restrict__ iminfo,  // (1,3)
    float4* __restrict__ keptBox,
    int*    __restrict__ keptRow,
    float*  __restrict__ keptScore,
    int*    __restrict__ ctrs,         // [0]=kept count, [1]=done count
    float*  __restrict__ out)
{
    __shared__ unsigned long long key[MAXC];   // keys; later the mask matrix
    __shared__ unsigned long long skey[MAXC];  // rank-sorted keys
    __shared__ float4 box4[MAXC];
    __shared__ float  areaA[MAXC];
    __shared__ unsigned char keepf[MAXC], supp[MAXC];
    __shared__ int hist[256];
    __shared__ int wtot[4];
    __shared__ unsigned s_pref;
    __shared__ int s_kk;
    __shared__ int mcnt, s_arr;                // total ~59.5 KB

    const int tid  = threadIdx.x;
    const int lane = tid & 63;
    const int wv   = tid >> 6;
    const int c = blockIdx.x + 1;   // class 1..80
    const int cbase = blockIdx.x * N_ROIS;

    if (tid == 0) mcnt = 0;
    __syncthreads();

    // --- compaction: batch-load prob column, then wave-ballot compact ---
    float sv[NCHUNK];
    #pragma unroll
    for (int t = 0; t < NCHUNK; ++t) {
        int i = t * TPB + tid;
        sv[t] = (i < N_ROIS) ? prob[i * NUM_CLS + c] : 0.0f;  // independent loads
    }
    #pragma unroll
    for (int t = 0; t < NCHUNK; ++t) {
        int i = t * TPB + tid;
        bool val = (i < N_ROIS) && (sv[t] > SCORE_T);
        unsigned long long m = __ballot(val);
        int base = 0;
        if (lane == 0 && m) base = atomicAdd(&mcnt, __popcll(m));
        base = __shfl(base, 0, 64);
        if (val) {
            int pos = base + __popcll(m & ((1ull << lane) - 1ull));
            key[pos] = ((unsigned long long)(~f2s(sv[t])) << 32) | (unsigned)i;
        }
    }

    // --- zero-fill this class's output region (float4; all 16B-aligned) ---
    {
        const float4 z4 = make_float4(0.f, 0.f, 0.f, 0.f);
        float4* dets4 = (float4*)(out + (size_t)cbase * 6);         // 2250
        for (int i = tid; i < N_ROIS * 6 / 4; i += TPB) dets4[i] = z4;
        const float fc = (float)c;
        const float4 c4 = make_float4(fc, fc, fc, fc);
        float4* cls4  = (float4*)(out + (size_t)TOTAL * 6 + cbase); // 375
        float4* keep4 = (float4*)(out + (size_t)TOTAL * 7 + cbase);
        for (int i = tid; i < N_ROIS / 4; i += TPB) { cls4[i] = c4; keep4[i] = z4; }
    }
    __syncthreads();
    const int M = mcnt;

    if (M > 0) {
        // --- rank-by-counting sort: keys unique -> ranks are a permutation ---
        for (int i = tid; i < M; i += TPB) {
            unsigned long long kk = key[i];
            int cnt = 0;
            #pragma unroll 4
            for (int j = 0; j < M; ++j) cnt += (int)(key[j] < kk);
            skey[cnt] = kk;
        }
        __syncthreads();

        // --- decode boxes at sorted positions (match numpy op-for-op) ---
        const float Hm1 = iminfo[0] - 1.0f;
        const float Wm1 = iminfo[1] - 1.0f;
        for (int k = tid; k < M; k += TPB) {
            unsigned long long kk = skey[k];
            int i = (int)(kk & 0xFFFFFFFFu);
            const float* rp = rois + i * 5;
            float x1 = rp[1], y1 = rp[2], x2 = rp[3], y2 = rp[4];
            float w  = x2 - x1 + 1.0f;
            float h  = y2 - y1 + 1.0f;
            float cx = x1 + 0.5f * w;
            float cy = y1 + 0.5f * h;
            const float* dp = deltas + i * (4 * NUM_CLS) + c * 4;
            float dx = dp[0] / 10.0f, dy = dp[1] / 10.0f;
            float dw = dp[2] / 5.0f,  dh = dp[3] / 5.0f;
            float pcx = cx + w * dx;
            float pcy = cy + h * dy;
            float pw  = w * expf(dw);
            float ph  = h * expf(dh);
            float a1 = pcx - 0.5f * pw;
            float a2 = pcy - 0.5f * ph;
            float a3 = pcx + 0.5f * pw - 1.0f;
            float a4 = pcy + 0.5f * ph - 1.0f;
            a1 = fminf(fmaxf(a1, 0.0f), Wm1);
            a2 = fminf(fmaxf(a2, 0.0f), Hm1);
            a3 = fminf(fmaxf(a3, 0.0f), Wm1);
            a4 = fminf(fmaxf(a4, 0.0f), Hm1);
            box4[k]  = make_float4(a1, a2, a3, a4);
            areaA[k] = (a3 - a1 + 1.0f) * (a4 - a2 + 1.0f);
            keepf[k] = 0; supp[k] = 0;
        }
        __syncthreads();

        const int MW = (M + 63) >> 6;          // 64-bit words per mask row
        const bool fast = (M * MW <= MAXC);    // mask matrix fits in key[]

        if (fast) {
            // --- suppression bit-matrix: row r, bit j iff j>r && iou>0.5 ---
            for (int r = wv; r < M; r += TPB / 64) {
                float4 br = box4[r];
                float  ar = areaA[r];
                for (int w = 0; w < MW; ++w) {
                    int col = (w << 6) | lane;
                    bool inb = (col < M);
                    int j = inb ? col : 0;
                    float4 bj = box4[j];
                    float  aj = areaA[j];
                    float iw = fminf(br.z, bj.z) - fmaxf(br.x, bj.x) + 1.0f;
                    float ih = fminf(br.w, bj.w) - fmaxf(br.y, bj.y) + 1.0f;
                    iw = fmaxf(iw, 0.0f);
                    ih = fmaxf(ih, 0.0f);
                    float inter = iw * ih;
                    float iou = inter / ((ar + aj) - inter);
                    bool pred = inb && (col > r) && (iou > NMS_T);
                    unsigned long long mk = __ballot(pred);
                    if (lane == 0) key[r * MW + w] = mk;
                }
            }
            __syncthreads();

            // --- serial scan, wave 0: prefetch next row's word so the LDS
            //     latency hides behind the shfl dependency chain ---
            if (tid < 64) {
                const int lw = (tid < MW) ? tid : 0;
                unsigned long long acc = 0;        // suppressed bits, word `tid`
                unsigned long long mcur = key[lw]; // row 0
                for (int k = 0; k < M; ++k) {
                    unsigned long long mnext =
                        (k + 1 < M) ? key[(k + 1) * MW + lw] : 0ull;
                    int bit = (int)((acc >> (k & 63)) & 1ull);
                    int sup = __shfl(bit, k >> 6, 64);
                    if (!sup) {                    // wave-uniform branch
                        acc |= mcur;
                        if (tid == 0) keepf[k] = 1;
                    }
                    mcur = mnext;
                }
            }
            __syncthreads();
        } else {
            // --- fallback: iterative greedy NMS (correct for any M) ---
            for (int k = 0; k < M; ++k) {
                if (!supp[k]) {
                    if (tid == 0) keepf[k] = 1;
                    float4 bk = box4[k];
                    float  ak = areaA[k];
                    for (int j = k + 1 + tid; j < M; j += TPB) {
                        float4 bj = box4[j];
                        float  aj = areaA[j];
                        float iw = fminf(bk.z, bj.z) - fmaxf(bk.x, bj.x) + 1.0f;
                        float ih = fminf(bk.w, bj.w) - fmaxf(bk.y, bj.y) + 1.0f;
                        iw = fmaxf(iw, 0.0f);
                        ih = fmaxf(ih, 0.0f);
                        float inter = iw * ih;
                        float iou = inter / ((ak + aj) - inter);
                        if (iou > NMS_T) supp[j] = 1;
                    }
                }
                __syncthreads();
            }
        }

        // --- push kept entries to global compact list ---
        for (int k = tid; k < M; k += TPB) {
            if (keepf[k]) {
                int p = atomicAdd(&ctrs[0], 1);
                keptRow[p]   = cbase + k;
                keptBox[p]   = box4[k];
                keptScore[p] = s2f(~(unsigned)(skey[k] >> 32));
            }
        }
    }

    // --- last-block-done: the final arriving block runs topk + scatter ---
    __threadfence();                           // release our pushes device-wide
    if (tid == 0) s_arr = atomicAdd(&ctrs[1], 1);
    __syncthreads();
    if (s_arr != FG - 1) return;
    __threadfence();                           // acquire all blocks' pushes

    const int n = ctrs[0];
    const bool filt = (n > MAX_DET);
    float kth = -INFINITY;

    if (filt) {
        // exact 100th-largest via MSB-first radix-256 select (tie-exact).
        // Digit selection is a parallel suffix-scan over the 256 bins:
        // thread v owns hist[v]; wave shfl suffix-scan + 4 wave totals give
        // S_ge(v) = count(digit >= v), S_gt(v) = count(digit > v); the
        // unique v with S_gt < kk <= S_ge is the digit.
        if (tid == 0) { s_pref = 0u; s_kk = MAX_DET; }
        __syncthreads();
        for (int d = 0; d < 4; ++d) {
            const int shift = 24 - 8 * d;
            hist[tid] = 0;                     // TPB == 256 bins exactly
            __syncthreads();
            const unsigned pref = s_pref;
            for (int i = tid; i < n; i += TPB) {
                unsigned u = f2s(keptScore[i]);  // L2-hot
                if (d == 0 || (u >> (shift + 8)) == pref)
                    atomicAdd(&hist[(u >> shift) & 255u], 1);
            }
            __syncthreads();
            const int h = hist[tid];
            int r = h;                          // wave suffix-scan (lane..63)
            #pragma unroll
            for (int off = 1; off < 64; off <<= 1) {
                int o = __shfl_down(r, off, 64);
                if (lane + off < 64) r += o;
            }
            if (lane == 0) wtot[wv] = r;
            __syncthreads();
            int hi = 0;
            #pragma unroll
            for (int w2 = 0; w2 < 4; ++w2) if (w2 > wv) hi += wtot[w2];
            const int S_ge = r + hi;
            const int S_gt = S_ge - h;
            const int kk = s_kk;
            if (S_gt < kk && S_ge >= kk) {      // exactly one thread
                s_pref = (pref << 8) | (unsigned)tid;
                s_kk   = kk - S_gt;
            }
            __syncthreads();
        }
        kth = s2f(s_pref);
    }

    for (int i = tid; i < n; i += TPB) {
        float s = keptScore[i];
        if (!filt || s >= kth) {
            int r = keptRow[i];
            float4 b4 = keptBox[i];
            float* dst = out + (size_t)r * 6;
            dst[1] = b4.x; dst[2] = b4.y; dst[3] = b4.z; dst[4] = b4.w; dst[5] = s;
            out[(size_t)TOTAL * 7 + r] = 1.0f;
        }
    }
}

extern "C" void kernel_launch(void* const* d_in, const int* in_sizes, int n_in,
                              void* d_out, int out_size, void* d_ws, size_t ws_size,
                              hipStream_t stream) {
    const float* rois   = (const float*)d_in[0];  // (1500,5)
    const float* deltas = (const float*)d_in[1];  // (1500,324)
    const float* prob   = (const float*)d_in[2];  // (1500,81)
    const float* iminfo = (const float*)d_in[3];  // (1,3)
    float* out = (float*)d_out;

    // workspace: float4 first for 16B alignment
    float4* keptBox   = (float4*)d_ws;                 // TOTAL entries
    int*    keptRow   = (int*)(keptBox + TOTAL);       // TOTAL
    float*  keptScore = (float*)(keptRow + TOTAL);     // TOTAL
    int*    ctrs      = (int*)(keptScore + TOTAL);     // [kept, done]

    hipMemsetAsync(ctrs, 0, 2 * sizeof(int), stream);
    nms_fused<<<FG, TPB, 0, stream>>>(rois, deltas, prob, iminfo,
                                      keptBox, keptRow, keptScore, ctrs, out);
}

// Round 8
// 109.533 us; speedup vs baseline: 1.1271x; 1.0755x over previous
//
#include <hip/hip_runtime.h>
#include <math.h>

#pragma clang fp contract(off)

#define N_ROIS     1500
#define NUM_CLS    81
#define FG         80
#define MAXC       1536      // per-class candidate capacity (worst case N_ROIS)
#define NMS_T      0.5f
#define SCORE_T    0.05f
#define MAX_DET    100
#define TOTAL      (FG * N_ROIS)
#define TPB        256
#define NCHUNK     ((N_ROIS + TPB - 1) / TPB)   // 6
#define SUBCAP     8192      // K2 LDS subset capacity

// float <-> order-preserving uint
__device__ __forceinline__ unsigned f2s(float f) {
    unsigned u = __float_as_uint(f);
    return (u & 0x80000000u) ? ~u : (u | 0x80000000u);
}
__device__ __forceinline__ float s2f(unsigned u) {
    return __uint_as_float((u & 0x80000000u) ? (u & 0x7FFFFFFFu) : ~u);
}

// ---------------- K1: per-class NMS (80 blocks) -------------------------
// wave-ballot compaction of valid (s > 0.05) -> rank-by-counting sort
// (keys unique: score desc, idx asc => exact stable order) -> decode valid
// boxes -> bitmask NMS (MxM bit-matrix via __ballot + register-only scan on
// wave 0; iterative fallback if matrix exceeds LDS) -> push kept entries.
// NO fences, NO output fills here: kernel boundary provides device-scope
// visibility (one release/acquire instead of 80 in-kernel __threadfence).
__global__ __launch_bounds__(TPB) void nms_k1(
    const float* __restrict__ rois,    // (N,5)
    const float* __restrict__ deltas,  // (N, 4*81)
    const float* __restrict__ prob,    // (N, 81)
    const float* __restrict__ iminfo,  // (1,3)
    float4* __restrict__ keptBox,
    int*    __restrict__ keptRow,
    float*  __restrict__ keptScore,
    int*    __restrict__ ctrs)         // [0]=kept count
{
    __shared__ unsigned long long key[MAXC];   // keys; later the mask matrix
    __shared__ unsigned long long skey[MAXC];  // rank-sorted keys
    __shared__ float4 box4[MAXC];
    __shared__ float  areaA[MAXC];
    __shared__ unsigned char keepf[MAXC], supp[MAXC];
    __shared__ int mcnt;

    const int tid  = threadIdx.x;
    const int lane = tid & 63;
    const int wv   = tid >> 6;
    const int c = blockIdx.x + 1;   // class 1..80
    const int cbase = blockIdx.x * N_ROIS;

    if (tid == 0) mcnt = 0;
    __syncthreads();

    // --- compaction: batch-load prob column, then wave-ballot compact ---
    float sv[NCHUNK];
    #pragma unroll
    for (int t = 0; t < NCHUNK; ++t) {
        int i = t * TPB + tid;
        sv[t] = (i < N_ROIS) ? prob[i * NUM_CLS + c] : 0.0f;
    }
    #pragma unroll
    for (int t = 0; t < NCHUNK; ++t) {
        int i = t * TPB + tid;
        bool val = (i < N_ROIS) && (sv[t] > SCORE_T);
        unsigned long long m = __ballot(val);
        int base = 0;
        if (lane == 0 && m) base = atomicAdd(&mcnt, __popcll(m));
        base = __shfl(base, 0, 64);
        if (val) {
            int pos = base + __popcll(m & ((1ull << lane) - 1ull));
            key[pos] = ((unsigned long long)(~f2s(sv[t])) << 32) | (unsigned)i;
        }
    }
    __syncthreads();
    const int M = mcnt;
    if (M == 0) return;

    // --- rank-by-counting sort: keys unique -> ranks are a permutation ---
    for (int i = tid; i < M; i += TPB) {
        unsigned long long kk = key[i];
        int cnt = 0;
        #pragma unroll 4
        for (int j = 0; j < M; ++j) cnt += (int)(key[j] < kk);
        skey[cnt] = kk;
    }
    __syncthreads();

    // --- decode boxes at sorted positions (match numpy op-for-op) ---
    const float Hm1 = iminfo[0] - 1.0f;
    const float Wm1 = iminfo[1] - 1.0f;
    for (int k = tid; k < M; k += TPB) {
        unsigned long long kk = skey[k];
        int i = (int)(kk & 0xFFFFFFFFu);
        const float* rp = rois + i * 5;
        float x1 = rp[1], y1 = rp[2], x2 = rp[3], y2 = rp[4];
        float w  = x2 - x1 + 1.0f;
        float h  = y2 - y1 + 1.0f;
        float cx = x1 + 0.5f * w;
        float cy = y1 + 0.5f * h;
        const float* dp = deltas + i * (4 * NUM_CLS) + c * 4;
        float dx = dp[0] / 10.0f, dy = dp[1] / 10.0f;
        float dw = dp[2] / 5.0f,  dh = dp[3] / 5.0f;
        float pcx = cx + w * dx;
        float pcy = cy + h * dy;
        float pw  = w * expf(dw);
        float ph  = h * expf(dh);
        float a1 = pcx - 0.5f * pw;
        float a2 = pcy - 0.5f * ph;
        float a3 = pcx + 0.5f * pw - 1.0f;
        float a4 = pcy + 0.5f * ph - 1.0f;
        a1 = fminf(fmaxf(a1, 0.0f), Wm1);
        a2 = fminf(fmaxf(a2, 0.0f), Hm1);
        a3 = fminf(fmaxf(a3, 0.0f), Wm1);
        a4 = fminf(fmaxf(a4, 0.0f), Hm1);
        box4[k]  = make_float4(a1, a2, a3, a4);
        areaA[k] = (a3 - a1 + 1.0f) * (a4 - a2 + 1.0f);
        keepf[k] = 0; supp[k] = 0;
    }
    __syncthreads();

    const int MW = (M + 63) >> 6;          // 64-bit words per mask row
    const bool fast = (M * MW <= MAXC);    // mask matrix fits in key[]

    if (fast) {
        // --- suppression bit-matrix: row r, bit j iff j>r && iou>0.5.
        //     Words w < r>>6 are identically zero: store 0, skip IoU. ---
        for (int r = wv; r < M; r += TPB / 64) {
            float4 br = box4[r];
            float  ar = areaA[r];
            const int w0 = r >> 6;
            if (lane == 0)
                for (int w = 0; w < w0; ++w) key[r * MW + w] = 0ull;
            for (int w = w0; w < MW; ++w) {
                int col = (w << 6) | lane;
                bool inb = (col < M);
                int j = inb ? col : 0;
                float4 bj = box4[j];
                float  aj = areaA[j];
                float iw = fminf(br.z, bj.z) - fmaxf(br.x, bj.x) + 1.0f;
                float ih = fminf(br.w, bj.w) - fmaxf(br.y, bj.y) + 1.0f;
                iw = fmaxf(iw, 0.0f);
                ih = fmaxf(ih, 0.0f);
                float inter = iw * ih;
                float iou = inter / ((ar + aj) - inter);
                bool pred = inb && (col > r) && (iou > NMS_T);
                unsigned long long mk = __ballot(pred);
                if (lane == 0) key[r * MW + w] = mk;
            }
        }
        __syncthreads();

        // --- serial scan, wave 0, prefetched register-only chain ---
        if (tid < 64) {
            const int lw = (tid < MW) ? tid : 0;
            unsigned long long acc = 0;        // suppressed bits, word `tid`
            unsigned long long mcur = key[lw]; // row 0
            for (int k = 0; k < M; ++k) {
                unsigned long long mnext =
                    (k + 1 < M) ? key[(k + 1) * MW + lw] : 0ull;
                int bit = (int)((acc >> (k & 63)) & 1ull);
                int sup = __shfl(bit, k >> 6, 64);
                if (!sup) {                    // wave-uniform branch
                    acc |= mcur;
                    if (tid == 0) keepf[k] = 1;
                }
                mcur = mnext;
            }
        }
        __syncthreads();
    } else {
        // --- fallback: iterative greedy NMS (correct for any M) ---
        for (int k = 0; k < M; ++k) {
            if (!supp[k]) {
                if (tid == 0) keepf[k] = 1;
                float4 bk = box4[k];
                float  ak = areaA[k];
                for (int j = k + 1 + tid; j < M; j += TPB) {
                    float4 bj = box4[j];
                    float  aj = areaA[j];
                    float iw = fminf(bk.z, bj.z) - fmaxf(bk.x, bj.x) + 1.0f;
                    float ih = fminf(bk.w, bj.w) - fmaxf(bk.y, bj.y) + 1.0f;
                    iw = fmaxf(iw, 0.0f);
                    ih = fmaxf(ih, 0.0f);
                    float inter = iw * ih;
                    float iou = inter / ((ak + aj) - inter);
                    if (iou > NMS_T) supp[j] = 1;
                }
            }
            __syncthreads();
        }
    }

    // --- push kept entries to global compact list ---
    for (int k = tid; k < M; k += TPB) {
        if (keepf[k]) {
            int p = atomicAdd(&ctrs[0], 1);
            keptRow[p]   = cbase + k;
            keptBox[p]   = box4[k];
            keptScore[p] = s2f(~(unsigned)(skey[k] >> 32));
        }
    }
}

// ---------------- K2: exact 100th-largest kept score (1 block) ----------
// Pass 1: 256-bin histogram of top-8 f2s digit (per-wave privatized),
// parallel suffix-scan digit pick. Pass 2: compact matching subset's lower
// 24 bits into LDS (ballot-aggregated append). Then 3 radix-256 rounds over
// the subset in LDS. Global fallback if subset exceeds LDS. Writes kth
// (-inf when n <= 100, so the patch kernel needs no flag). Tie-exact.
__global__ __launch_bounds__(TPB) void kth_k2(
    const int*   __restrict__ ctrs,
    const float* __restrict__ keptScore,
    float* __restrict__ kth_out)
{
    __shared__ int hist4[4][256];     // 4 KB
    __shared__ unsigned sub[SUBCAP];  // 32 KB
    __shared__ int wtot[4];
    __shared__ unsigned s_d0;
    __shared__ unsigned s_sp;         // accumulated lower-prefix (rounds 1..3)
    __shared__ int s_kk, s_cnt;

    const int tid  = threadIdx.x;
    const int lane = tid & 63;
    const int wv   = tid >> 6;
    const int n = ctrs[0];

    if (n <= MAX_DET) {
        if (tid == 0) *kth_out = -INFINITY;
        return;
    }

    // --- pass 1: top-8-digit histogram, per-wave privatized ---
    #pragma unroll
    for (int w = 0; w < 4; ++w) hist4[w][tid] = 0;
    __syncthreads();
    for (int i = tid; i < n; i += TPB)
        atomicAdd(&hist4[wv][f2s(keptScore[i]) >> 24], 1);
    __syncthreads();
    {
        const int h = hist4[0][tid] + hist4[1][tid] + hist4[2][tid] + hist4[3][tid];
        int r = h;                              // wave suffix-scan (lane..63)
        #pragma unroll
        for (int off = 1; off < 64; off <<= 1) {
            int o = __shfl_down(r, off, 64);
            if (lane + off < 64) r += o;
        }
        if (lane == 0) wtot[wv] = r;
        __syncthreads();
        int hi = 0;
        #pragma unroll
        for (int w2 = 0; w2 < 4; ++w2) if (w2 > wv) hi += wtot[w2];
        const int S_ge = r + hi, S_gt = S_ge - h;
        if (S_gt < MAX_DET && S_ge >= MAX_DET) {  // exactly one thread
            s_d0 = (unsigned)tid;
            s_kk = MAX_DET - S_gt;
        }
    }
    if (tid == 0) { s_cnt = 0; s_sp = 0u; }
    __syncthreads();
    const unsigned d0 = s_d0;

    // --- pass 2: compact lower-24 bits of matching subset into LDS ---
    for (int i0 = 0; i0 < n; i0 += TPB) {
        int i = i0 + tid;
        unsigned u = (i < n) ? f2s(keptScore[i]) : 0u;
        bool match = (i < n) && ((u >> 24) == d0);
        unsigned long long m = __ballot(match);
        int base = 0;
        if (lane == 0 && m) base = atomicAdd(&s_cnt, __popcll(m));
        base = __shfl(base, 0, 64);
        if (match) {
            int pos = base + __popcll(m & ((1ull << lane) - 1ull));
            if (pos < SUBCAP) sub[pos] = u & 0xFFFFFFu;
        }
    }
    __syncthreads();
    const int ns = s_cnt;
    const bool inLds = (ns <= SUBCAP);
    const int limit = inLds ? ns : n;

    // --- rounds 1..3 over the 24 remaining bits ---
    for (int d = 1; d < 4; ++d) {
        const int shift = 24 - 8 * d;            // 16, 8, 0
        #pragma unroll
        for (int w = 0; w < 4; ++w) hist4[w][tid] = 0;
        __syncthreads();
        const unsigned sp = s_sp;
        for (int i = tid; i < limit; i += TPB) {
            unsigned v; bool ok;
            if (inLds) { v = sub[i]; ok = true; }
            else {
                unsigned u = f2s(keptScore[i]);
                ok = ((u >> 24) == d0);
                v = u & 0xFFFFFFu;
            }
            if (ok && (d == 1 || (v >> (shift + 8)) == sp))
                atomicAdd(&hist4[wv][(v >> shift) & 255u], 1);
        }
        __syncthreads();
        const int h = hist4[0][tid] + hist4[1][tid] + hist4[2][tid] + hist4[3][tid];
        int r = h;
        #pragma unroll
        for (int off = 1; off < 64; off <<= 1) {
            int o = __shfl_down(r, off, 64);
            if (lane + off < 64) r += o;
        }
        if (lane == 0) wtot[wv] = r;
        __syncthreads();
        int hi = 0;
        #pragma unroll
        for (int w2 = 0; w2 < 4; ++w2) if (w2 > wv) hi += wtot[w2];
        const int S_ge = r + hi, S_gt = S_ge - h;
        const int kk = s_kk;
        if (S_gt < kk && S_ge >= kk) {            // exactly one thread
            s_sp = (s_sp << 8) | (unsigned)tid;
            s_kk = kk - S_gt;
        }
        __syncthreads();
    }

    if (tid == 0) *kth_out = s2f((d0 << 24) | s_sp);
}

// ---------------- K3: parallel output fill (grid-stride float4) ---------
// dets = 0; cls_idx = r/1500 + 1; keep = 0. 1500 % 4 == 0, so no float4
// straddles a class boundary.
__global__ __launch_bounds__(TPB) void fill_k3(float* __restrict__ out)
{
    const float4 z4 = make_float4(0.f, 0.f, 0.f, 0.f);
    const int stride = gridDim.x * TPB;
    int g = blockIdx.x * TPB + threadIdx.x;

    float4* dets4 = (float4*)out;                      // TOTAL*6/4 = 180000
    for (int i = g; i < TOTAL * 6 / 4; i += stride) dets4[i] = z4;

    float4* cls4  = (float4*)(out + (size_t)TOTAL * 6); // TOTAL/4 = 30000
    float4* keep4 = (float4*)(out + (size_t)TOTAL * 7);
    for (int i = g; i < TOTAL / 4; i += stride) {
        float fc = (float)((i * 4) / N_ROIS + 1);
        cls4[i]  = make_float4(fc, fc, fc, fc);
        keep4[i] = z4;
    }
}

// ---------------- K4: parallel patch of kept rows (grid-stride) ---------
__global__ __launch_bounds__(TPB) void patch_k4(
    const int*    __restrict__ ctrs,
    const int*    __restrict__ keptRow,
    const float4* __restrict__ keptBox,
    const float*  __restrict__ keptScore,
    const float*  __restrict__ kth_ptr,
    float* __restrict__ out)
{
    const int n = ctrs[0];
    const float kth = *kth_ptr;      // -inf when no filtering
    const int stride = gridDim.x * TPB;
    for (int i = blockIdx.x * TPB + threadIdx.x; i < n; i += stride) {
        float s = keptScore[i];
        if (s >= kth) {
            int r = keptRow[i];
            float4 b4 = keptBox[i];
            float* dst = out + (size_t)r * 6;
            dst[1] = b4.x; dst[2] = b4.y; dst[3] = b4.z; dst[4] = b4.w; dst[5] = s;
            out[(size_t)TOTAL * 7 + r] = 1.0f;
        }
    }
}

extern "C" void kernel_launch(void* const* d_in, const int* in_sizes, int n_in,
                              void* d_out, int out_size, void* d_ws, size_t ws_size,
                              hipStream_t stream) {
    const float* rois   = (const float*)d_in[0];  // (1500,5)
    const float* deltas = (const float*)d_in[1];  // (1500,324)
    const float* prob   = (const float*)d_in[2];  // (1500,81)
    const float* iminfo = (const float*)d_in[3];  // (1,3)
    float* out = (float*)d_out;

    // workspace: float4 first for 16B alignment
    float4* keptBox   = (float4*)d_ws;                 // TOTAL entries
    int*    keptRow   = (int*)(keptBox + TOTAL);       // TOTAL
    float*  keptScore = (float*)(keptRow + TOTAL);     // TOTAL
    int*    ctrs      = (int*)(keptScore + TOTAL);     // [kept]
    float*  kth       = (float*)(ctrs + 4);            // 1 (16B-aligned pad)

    hipMemsetAsync(ctrs, 0, sizeof(int), stream);
    nms_k1<<<FG, TPB, 0, stream>>>(rois, deltas, prob, iminfo,
                                   keptBox, keptRow, keptScore, ctrs);
    kth_k2<<<1, TPB, 0, stream>>>(ctrs, keptScore, kth);
    fill_k3<<<256, TPB, 0, stream>>>(out);
    patch_k4<<<64, TPB, 0, stream>>>(ctrs, keptRow, keptBox, keptScore, kth, out);
}